// Round 14
// baseline (75.943 us; speedup 1.0000x reference)
//
#include <hip/hip_runtime.h>
#include <math.h>

#define B_  2048
#define T_  200
#define D_  64
#define H1_ 80
#define H2_ 40

#define WSTR 104   // W2T row stride (bf16): 208 B rows -> ~2-way banks
#define HSTR 104   // h1 row stride (bf16); cols 80..95 zero pad

// d_ws layout (bytes):
#define WS_A    0        // A[h][f]  bf16 [80][64]
#define WS_C    10240    // C[h][f]  bf16 [80][64]
#define WS_W2T  20480    // W2Tp[g][h] bf16 [48][104]
#define WS_ACT  30464    // W1acT[h][f] f32 [80][64]

typedef __bf16 bf16x8 __attribute__((ext_vector_type(8)));
typedef float  f32x4  __attribute__((ext_vector_type(4)));

__device__ __forceinline__ float sigmoidf_(float x) {
    return __builtin_amdgcn_rcpf(1.0f + __expf(-x));
}

// ---------- prep: block-invariant weight transforms ----------
__global__ __launch_bounds__(256)
void prep_kernel(const float* __restrict__ W1, const float* __restrict__ W2,
                 void* __restrict__ ws)
{
    __bf16* A    = (__bf16*)((char*)ws + WS_A);
    __bf16* C    = (__bf16*)((char*)ws + WS_C);
    __bf16* W2Tp = (__bf16*)((char*)ws + WS_W2T);
    float*  acT  = (float*)((char*)ws + WS_ACT);
    const int e0 = blockIdx.x * 256 + threadIdx.x;

    for (int e = e0; e < H1_ * D_; e += 2048) {
        int h = e >> 6, f = e & 63;
        float wb = W1[(64  + f) * H1_ + h];
        float wc = W1[(128 + f) * H1_ + h];
        float wd = W1[(192 + f) * H1_ + h];
        float wa = W1[f * H1_ + h];
        A[e]   = (__bf16)(wb - wc);
        C[e]   = (__bf16)wd;
        acT[e] = wa + wc;
    }
    for (int e = e0; e < 48 * WSTR; e += 2048) {
        int g = e / WSTR, h = e - g * WSTR;
        W2Tp[e] = (g < H2_ && h < H1_) ? (__bf16)W2[h * H2_ + g] : (__bf16)0.0f;
    }
}

// ---------- main: one batch per 2-wave block, per-wave flash, bw in LDS / bv in regs ----------
__global__ __launch_bounds__(128, 3)
void attn_din14(const float* __restrict__ query,
                const float* __restrict__ key,
                const int*   __restrict__ mask,
                const float* __restrict__ b1,
                const float* __restrict__ b2,
                const float* __restrict__ W3,
                const float* __restrict__ b3,
                const void*  __restrict__ ws,
                float* __restrict__ out)
{
    __shared__ __align__(16) __bf16 s_W2T[48 * WSTR];    //  9984 B (block-shared)
    __shared__ __align__(16) __bf16 s_h1[2][16 * HSTR];  //  6656 B (per-wave)
    __shared__ __align__(16) float  s_q[D_];             //   256 B
    __shared__ float s_base[H1_];                         //   320 B
    __shared__ float s_sc16[2][16];                       //   128 B
    __shared__ float s_part[2][D_];                       //   512 B
    __shared__ float s_ml[2][2];
    // ~17.9 KB -> 6 blocks/CU at 3 waves/SIMD

    const int tid  = threadIdx.x;          // 0..127
    const int lane = tid & 63;
    const int w    = tid >> 6;             // wave 0/1
    const int c16  = lane & 15;
    const int g16  = lane >> 4;
    const int b    = blockIdx.x;

    const int   mv     = mask[b];
    const int   ntiles = (mv + 15) >> 4;
    const float b3v    = b3[0];
    const float* kb = key + (size_t)b * T_ * D_;

    const __bf16* wsA   = (const __bf16*)((const char*)ws + WS_A);
    const __bf16* wsC   = (const __bf16*)((const char*)ws + WS_C);
    const uint4*  wsW2T = (const uint4*) ((const char*)ws + WS_W2T);
    const float*  wsacT = (const float*) ((const char*)ws + WS_ACT);

    // ---- stage q; copy W2T to LDS (624 16B chunks over 128 threads) ----
    if (tid < D_) s_q[tid] = query[b * D_ + tid];
    {
        uint4* dst = (uint4*)s_W2T;
        #pragma unroll
        for (int i = 0; i < 5; ++i) {
            int e = tid + 128 * i;
            if (e < 624) dst[e] = wsW2T[e];
        }
    }

    float b2c[3], w3c[3];
    #pragma unroll
    for (int nt = 0; nt < 3; ++nt) {
        int g = nt * 16 + c16;
        b2c[nt] = (g < H2_) ? b2[g] : 0.0f;
        w3c[nt] = (g < H2_) ? W3[g] : 0.0f;
    }
    __syncthreads();   // q visible

    // ---- base[h] (threads 0..79) ----
    if (tid < H1_) {
        float a0 = b1[tid], a1 = 0.0f, a2 = 0.0f, a3 = 0.0f;
        const f32x4* row = (const f32x4*)&wsacT[tid * D_];
        #pragma unroll
        for (int f4 = 0; f4 < 16; ++f4) {
            f32x4 v  = row[f4];
            f32x4 q4 = *(const f32x4*)&s_q[f4 * 4];
            a0 = fmaf(q4[0], v[0], a0);
            a1 = fmaf(q4[1], v[1], a1);
            a2 = fmaf(q4[2], v[2], a2);
            a3 = fmaf(q4[3], v[3], a3);
        }
        s_base[tid] = (a0 + a1) + (a2 + a3);
    }

    // ---- bv[5][2] in registers: V at (h = nt*16+c16, f = ks*32+g16*8+j) ----
    bf16x8 bv[5][2];
    #pragma unroll
    for (int nt = 0; nt < 5; ++nt)
        #pragma unroll
        for (int ks = 0; ks < 2; ++ks) {
            int off = (nt * 16 + c16) * D_ + ks * 32 + g16 * 8;
            bf16x8 a8 = *(const bf16x8*)&wsA[off];
            bf16x8 c8 = *(const bf16x8*)&wsC[off];
            f32x4 q0 = *(const f32x4*)&s_q[ks * 32 + g16 * 8];
            f32x4 q1 = *(const f32x4*)&s_q[ks * 32 + g16 * 8 + 4];
            bf16x8 v8;
            v8[0] = (__bf16)((float)a8[0] + q0[0] * (float)c8[0]);
            v8[1] = (__bf16)((float)a8[1] + q0[1] * (float)c8[1]);
            v8[2] = (__bf16)((float)a8[2] + q0[2] * (float)c8[2]);
            v8[3] = (__bf16)((float)a8[3] + q0[3] * (float)c8[3]);
            v8[4] = (__bf16)((float)a8[4] + q1[0] * (float)c8[4]);
            v8[5] = (__bf16)((float)a8[5] + q1[1] * (float)c8[5]);
            v8[6] = (__bf16)((float)a8[6] + q1[2] * (float)c8[6]);
            v8[7] = (__bf16)((float)a8[7] + q1[3] * (float)c8[7]);
            bv[nt][ks] = v8;
        }

    // ---- zero h1 pad cols 80..95 (own wave region) ----
    {
        int row = lane & 15, c0 = 80 + (lane >> 4) * 4;
        *(uint2*)&s_h1[w][row * HSTR + c0] = make_uint2(0u, 0u);
    }
    __syncthreads();   // base, W2T visible

    float base_c[5];
    #pragma unroll
    for (int nt = 0; nt < 5; ++nt) base_c[nt] = s_base[nt * 16 + c16];
    __bf16* myh = &s_h1[w][0];

    // ---- prologue key load for first own-parity tile (clamped rows) ----
    float4 u0, u1, u2, u3;
    {
        int tr = w * 16 + c16;
        const float* kr = kb + (size_t)((tr < T_) ? tr : (T_ - 1)) * D_ + g16 * 8;
        u0 = *(const float4*)(kr);
        u1 = *(const float4*)(kr + 4);
        u2 = *(const float4*)(kr + 32);
        u3 = *(const float4*)(kr + 36);
    }

    // ---- per-wave flash state ----
    float o00,o01,o02,o03,o04,o05,o06,o07,o08,o09,o10,o11,o12,o13,o14,o15;
    o00=o01=o02=o03=o04=o05=o06=o07=o08=o09=o10=o11=o12=o13=o14=o15=0.0f;
    float m_run = -1e30f, l_run = 0.0f;

    // ---------------- main loop: own-parity tiles, no barriers ----------------
    for (int tt = w; tt < ntiles; tt += 2) {
        bf16x8 af0, af1;
        af0[0] = (__bf16)u0.x; af0[1] = (__bf16)u0.y; af0[2] = (__bf16)u0.z; af0[3] = (__bf16)u0.w;
        af0[4] = (__bf16)u1.x; af0[5] = (__bf16)u1.y; af0[6] = (__bf16)u1.z; af0[7] = (__bf16)u1.w;
        af1[0] = (__bf16)u2.x; af1[1] = (__bf16)u2.y; af1[2] = (__bf16)u2.z; af1[3] = (__bf16)u2.w;
        af1[4] = (__bf16)u3.x; af1[5] = (__bf16)u3.y; af1[6] = (__bf16)u3.z; af1[7] = (__bf16)u3.w;

        // T14 prefetch next own-parity tile
        if (tt + 2 < ntiles) {
            int tr = (tt + 2) * 16 + c16;
            const float* kr = kb + (size_t)((tr < T_) ? tr : (T_ - 1)) * D_ + g16 * 8;
            u0 = *(const float4*)(kr);
            u1 = *(const float4*)(kr + 4);
            u2 = *(const float4*)(kr + 32);
            u3 = *(const float4*)(kr + 36);
        }

        // layer 1 -> sigmoid -> h1 (own-wave region; B from registers)
        #pragma unroll
        for (int nt = 0; nt < 5; ++nt) {
            float bb = base_c[nt];
            f32x4 c = { bb, bb, bb, bb };
            c = __builtin_amdgcn_mfma_f32_16x16x32_bf16(af0, bv[nt][0], c, 0, 0, 0);
            c = __builtin_amdgcn_mfma_f32_16x16x32_bf16(af1, bv[nt][1], c, 0, 0, 0);
            #pragma unroll
            for (int r = 0; r < 4; ++r)
                myh[(g16 * 4 + r) * HSTR + nt * 16 + c16] = (__bf16)sigmoidf_(c[r]);
        }

        // layer 2 (k=0..95 incl. zero pad), B from LDS
        bf16x8 a2_0 = *(const bf16x8*)&myh[c16 * HSTR + g16 * 8];
        bf16x8 a2_1 = *(const bf16x8*)&myh[c16 * HSTR + 32 + g16 * 8];
        bf16x8 a2_2 = *(const bf16x8*)&myh[c16 * HSTR + 64 + g16 * 8];
        f32x4 acc2[3];
        #pragma unroll
        for (int nt = 0; nt < 3; ++nt) {
            float bb = b2c[nt];
            f32x4 c = { bb, bb, bb, bb };
            bf16x8 w0 = *(const bf16x8*)&s_W2T[(nt * 16 + c16) * WSTR + g16 * 8];
            bf16x8 w1 = *(const bf16x8*)&s_W2T[(nt * 16 + c16) * WSTR + 32 + g16 * 8];
            bf16x8 w2 = *(const bf16x8*)&s_W2T[(nt * 16 + c16) * WSTR + 64 + g16 * 8];
            c = __builtin_amdgcn_mfma_f32_16x16x32_bf16(a2_0, w0, c, 0, 0, 0);
            c = __builtin_amdgcn_mfma_f32_16x16x32_bf16(a2_1, w1, c, 0, 0, 0);
            c = __builtin_amdgcn_mfma_f32_16x16x32_bf16(a2_2, w2, c, 0, 0, 0);
            acc2[nt] = c;
        }

        // layer 3 + masked score -> s_sc16 (own wave)
        const int tb = tt * 16;
        #pragma unroll
        for (int r = 0; r < 4; ++r) {
            float partial = sigmoidf_(acc2[0][r]) * w3c[0]
                          + sigmoidf_(acc2[1][r]) * w3c[1]
                          + sigmoidf_(acc2[2][r]) * w3c[2];
            partial += __shfl_xor(partial, 1);
            partial += __shfl_xor(partial, 2);
            partial += __shfl_xor(partial, 4);
            partial += __shfl_xor(partial, 8);
            if (c16 == 0) {
                int t = tb + g16 * 4 + r;
                s_sc16[w][g16 * 4 + r] = (t < mv) ? (partial + b3v) * 0.125f : -1e30f;
            }
        }

        // online softmax update (lane's row t = tb + c16; key values from af)
        float s = s_sc16[w][c16];
        float tm = s;
        tm = fmaxf(tm, __shfl_xor(tm, 1));
        tm = fmaxf(tm, __shfl_xor(tm, 2));
        tm = fmaxf(tm, __shfl_xor(tm, 4));
        tm = fmaxf(tm, __shfl_xor(tm, 8));
        float m_new = fmaxf(m_run, tm);
        float alpha = __expf(m_run - m_new);
        float p = __expf(s - m_new);
        float psum = p;
        psum += __shfl_xor(psum, 1);
        psum += __shfl_xor(psum, 2);
        psum += __shfl_xor(psum, 4);
        psum += __shfl_xor(psum, 8);
        l_run = l_run * alpha + psum;
        o00 = fmaf(p, (float)af0[0], o00 * alpha);  o01 = fmaf(p, (float)af0[1], o01 * alpha);
        o02 = fmaf(p, (float)af0[2], o02 * alpha);  o03 = fmaf(p, (float)af0[3], o03 * alpha);
        o04 = fmaf(p, (float)af0[4], o04 * alpha);  o05 = fmaf(p, (float)af0[5], o05 * alpha);
        o06 = fmaf(p, (float)af0[6], o06 * alpha);  o07 = fmaf(p, (float)af0[7], o07 * alpha);
        o08 = fmaf(p, (float)af1[0], o08 * alpha);  o09 = fmaf(p, (float)af1[1], o09 * alpha);
        o10 = fmaf(p, (float)af1[2], o10 * alpha);  o11 = fmaf(p, (float)af1[3], o11 * alpha);
        o12 = fmaf(p, (float)af1[4], o12 * alpha);  o13 = fmaf(p, (float)af1[5], o13 * alpha);
        o14 = fmaf(p, (float)af1[6], o14 * alpha);  o15 = fmaf(p, (float)af1[7], o15 * alpha);
        m_run = m_new;
    }

    // ---------------- per-wave finalize: reduce o over c16 lanes ----------------
    #define ORED(X) X += __shfl_xor(X,1); X += __shfl_xor(X,2); X += __shfl_xor(X,4); X += __shfl_xor(X,8);
    ORED(o00) ORED(o01) ORED(o02) ORED(o03) ORED(o04) ORED(o05) ORED(o06) ORED(o07)
    ORED(o08) ORED(o09) ORED(o10) ORED(o11) ORED(o12) ORED(o13) ORED(o14) ORED(o15)
    #undef ORED
    if (c16 == 0) {
        float* sp = &s_part[w][0];
        sp[g16 * 8 + 0] = o00;  sp[g16 * 8 + 1] = o01;
        sp[g16 * 8 + 2] = o02;  sp[g16 * 8 + 3] = o03;
        sp[g16 * 8 + 4] = o04;  sp[g16 * 8 + 5] = o05;
        sp[g16 * 8 + 6] = o06;  sp[g16 * 8 + 7] = o07;
        sp[32 + g16 * 8 + 0] = o08;  sp[32 + g16 * 8 + 1] = o09;
        sp[32 + g16 * 8 + 2] = o10;  sp[32 + g16 * 8 + 3] = o11;
        sp[32 + g16 * 8 + 4] = o12;  sp[32 + g16 * 8 + 5] = o13;
        sp[32 + g16 * 8 + 6] = o14;  sp[32 + g16 * 8 + 7] = o15;
    }
    if (lane == 0) { s_ml[w][0] = m_run; s_ml[w][1] = l_run; }
    __syncthreads();

    // ---------------- cross-wave flash merge (threads 0..63) ----------------
    if (tid < D_) {
        float m0 = s_ml[0][0], l0 = s_ml[0][1];
        float m1 = s_ml[1][0], l1 = s_ml[1][1];
        float mm = fmaxf(m0, m1);
        float f0 = __expf(m0 - mm);
        float f1 = __expf(m1 - mm);
        float tot = l0 * f0 + l1 * f1;
        out[b * D_ + tid] = (s_part[0][tid] * f0 + s_part[1][tid] * f1)
                          * __builtin_amdgcn_rcpf(tot);
    }
}

extern "C" void kernel_launch(void* const* d_in, const int* in_sizes, int n_in,
                              void* d_out, int out_size, void* d_ws, size_t ws_size,
                              hipStream_t stream)
{
    const float* query = (const float*)d_in[0];
    const float* key   = (const float*)d_in[1];
    const int*   mask  = (const int*)  d_in[2];
    const float* W1    = (const float*)d_in[3];
    const float* b1    = (const float*)d_in[4];
    const float* W2    = (const float*)d_in[5];
    const float* b2    = (const float*)d_in[6];
    const float* W3    = (const float*)d_in[7];
    const float* b3    = (const float*)d_in[8];
    float* out = (float*)d_out;

    prep_kernel<<<8, 256, 0, stream>>>(W1, W2, d_ws);
    attn_din14<<<B_, 128, 0, stream>>>(query, key, mask, b1, b2, W3, b3, d_ws, out);
}

// Round 15
// 53.246 us; speedup vs baseline: 1.4263x; 1.4263x over previous
//
#include <hip/hip_runtime.h>
#include <math.h>

#define B_  2048
#define T_  200
#define D_  64
#define H1_ 80
#define H2_ 40

#define WSTR 104   // ws W2T row stride (bf16)
#define HSTR 104   // h1 row stride (bf16); cols 80..95 zero pad
#define HBUF (16 * HSTR)

// d_ws layout (bytes):
#define WS_A    0        // A[h][f]  bf16 [80][64]
#define WS_C    10240    // C[h][f]  bf16 [80][64]
#define WS_W2T  20480    // W2Tp[g][h] bf16 [48][104]
#define WS_ACT  30464    // W1acT[h][f] f32 [80][64]

typedef __bf16 bf16x8 __attribute__((ext_vector_type(8)));
typedef float  f32x4  __attribute__((ext_vector_type(4)));

__device__ __forceinline__ float sigmoidf_(float x) {
    return __builtin_amdgcn_rcpf(1.0f + __expf(-x));
}

// ---------- prep: block-invariant weight transforms ----------
__global__ __launch_bounds__(256)
void prep_kernel(const float* __restrict__ W1, const float* __restrict__ W2,
                 void* __restrict__ ws)
{
    __bf16* A    = (__bf16*)((char*)ws + WS_A);
    __bf16* C    = (__bf16*)((char*)ws + WS_C);
    __bf16* W2Tp = (__bf16*)((char*)ws + WS_W2T);
    float*  acT  = (float*)((char*)ws + WS_ACT);
    const int e0 = blockIdx.x * 256 + threadIdx.x;

    for (int e = e0; e < H1_ * D_; e += 2048) {
        int h = e >> 6, f = e & 63;
        float wb = W1[(64  + f) * H1_ + h];
        float wc = W1[(128 + f) * H1_ + h];
        float wd = W1[(192 + f) * H1_ + h];
        float wa = W1[f * H1_ + h];
        A[e]   = (__bf16)(wb - wc);
        C[e]   = (__bf16)wd;
        acT[e] = wa + wc;
    }
    for (int e = e0; e < 48 * WSTR; e += 2048) {
        int g = e / WSTR, h = e - g * WSTR;
        W2Tp[e] = (g < H2_ && h < H1_) ? (__bf16)W2[h * H2_ + g] : (__bf16)0.0f;
    }
}

// ---------- main: one batch per wave, double-buffered h1 software pipeline ----------
__global__ __launch_bounds__(256, 2)
void attn_din15(const float* __restrict__ query,
                const float* __restrict__ key,
                const int*   __restrict__ mask,
                const float* __restrict__ b1,
                const float* __restrict__ b2,
                const float* __restrict__ W3,
                const float* __restrict__ b3,
                const void*  __restrict__ ws,
                float* __restrict__ out)
{
    __shared__ __align__(16) __bf16 s_h1[4][2][HBUF];    // 26624 B (per-wave, dbuf)
    __shared__ __align__(16) float  s_q[4][D_];
    __shared__ float s_base[4][H1_];
    __shared__ float s_sc16[4][16];
    __shared__ float s_part[4][D_];
    // ~30 KB

    const int tid  = threadIdx.x;
    const int lane = tid & 63;
    const int w    = tid >> 6;
    const int c16  = lane & 15;
    const int g16  = lane >> 4;
    const int b    = blockIdx.x * 4 + w;       // wave-private batch

    const int   mv     = mask[b];
    const int   ntiles = (mv + 15) >> 4;
    const float b3v    = b3[0];
    const float* kb = key + (size_t)b * T_ * D_;

    const __bf16* wsA   = (const __bf16*)((const char*)ws + WS_A);
    const __bf16* wsC   = (const __bf16*)((const char*)ws + WS_C);
    const __bf16* wsW2T = (const __bf16*)((const char*)ws + WS_W2T);
    const float*  wsacT = (const float*) ((const char*)ws + WS_ACT);

    // ---- issue q + tile-0 key loads early ----
    float qv = query[b * D_ + lane];
    float4 u0, u1, u2, u3;
    {
        const float* kr = kb + (size_t)c16 * D_ + g16 * 8;  // tile 0 (mv>=1)
        u0 = *(const float4*)(kr);
        u1 = *(const float4*)(kr + 4);
        u2 = *(const float4*)(kr + 32);
        u3 = *(const float4*)(kr + 36);
    }
    s_q[w][lane] = qv;

    // ---- W2T fragments into registers (L2-resident ws) ----
    bf16x8 bw[3][3];
    #pragma unroll
    for (int nt = 0; nt < 3; ++nt)
        #pragma unroll
        for (int ks = 0; ks < 3; ++ks)
            bw[nt][ks] = *(const bf16x8*)&wsW2T[(nt * 16 + c16) * WSTR + ks * 32 + g16 * 8];

    float b2c[3], w3c[3];
    #pragma unroll
    for (int nt = 0; nt < 3; ++nt) {
        int g = nt * 16 + c16;
        b2c[nt] = (g < H2_) ? b2[g] : 0.0f;
        w3c[nt] = (g < H2_) ? W3[g] : 0.0f;
    }

    // ---- base[h] ----
    {
        float a0 = b1[lane], a1 = 0.0f, a2 = 0.0f, a3 = 0.0f;
        const f32x4* row = (const f32x4*)&wsacT[lane * D_];
        #pragma unroll
        for (int f4 = 0; f4 < 16; ++f4) {
            f32x4 v  = row[f4];
            f32x4 q4 = *(const f32x4*)&s_q[w][f4 * 4];
            a0 = fmaf(q4[0], v[0], a0);
            a1 = fmaf(q4[1], v[1], a1);
            a2 = fmaf(q4[2], v[2], a2);
            a3 = fmaf(q4[3], v[3], a3);
        }
        s_base[w][lane] = (a0 + a1) + (a2 + a3);
    }
    if (lane < 16) {
        int h = 64 + lane;
        float a0 = b1[h], a1 = 0.0f, a2 = 0.0f, a3 = 0.0f;
        const f32x4* row = (const f32x4*)&wsacT[h * D_];
        #pragma unroll
        for (int f4 = 0; f4 < 16; ++f4) {
            f32x4 v  = row[f4];
            f32x4 q4 = *(const f32x4*)&s_q[w][f4 * 4];
            a0 = fmaf(q4[0], v[0], a0);
            a1 = fmaf(q4[1], v[1], a1);
            a2 = fmaf(q4[2], v[2], a2);
            a3 = fmaf(q4[3], v[3], a3);
        }
        s_base[w][h] = (a0 + a1) + (a2 + a3);
    }

    // ---- bv[5][2] B-fragments in registers ----
    bf16x8 bv[5][2];
    #pragma unroll
    for (int nt = 0; nt < 5; ++nt)
        #pragma unroll
        for (int ks = 0; ks < 2; ++ks) {
            int off = (nt * 16 + c16) * D_ + ks * 32 + g16 * 8;
            bf16x8 a8 = *(const bf16x8*)&wsA[off];
            bf16x8 c8 = *(const bf16x8*)&wsC[off];
            f32x4 q0 = *(const f32x4*)&s_q[w][ks * 32 + g16 * 8];
            f32x4 q1 = *(const f32x4*)&s_q[w][ks * 32 + g16 * 8 + 4];
            bf16x8 v8;
            v8[0] = (__bf16)((float)a8[0] + q0[0] * (float)c8[0]);
            v8[1] = (__bf16)((float)a8[1] + q0[1] * (float)c8[1]);
            v8[2] = (__bf16)((float)a8[2] + q0[2] * (float)c8[2]);
            v8[3] = (__bf16)((float)a8[3] + q0[3] * (float)c8[3]);
            v8[4] = (__bf16)((float)a8[4] + q1[0] * (float)c8[4]);
            v8[5] = (__bf16)((float)a8[5] + q1[1] * (float)c8[5]);
            v8[6] = (__bf16)((float)a8[6] + q1[2] * (float)c8[6]);
            v8[7] = (__bf16)((float)a8[7] + q1[3] * (float)c8[7]);
            bv[nt][ks] = v8;
        }

    // ---- zero h1 pad cols 80..95 for BOTH buffers ----
    {
        int row = lane & 15, c0 = 80 + (lane >> 4) * 4;
        *(uint2*)&s_h1[w][0][row * HSTR + c0] = make_uint2(0u, 0u);
        *(uint2*)&s_h1[w][1][row * HSTR + c0] = make_uint2(0u, 0u);
    }

    float base_c[5];
    #pragma unroll
    for (int nt = 0; nt < 5; ++nt) base_c[nt] = s_base[w][nt * 16 + c16];
    __bf16* const myh0 = &s_h1[w][0][0];

    // ---- flash state ----
    float o00,o01,o02,o03,o04,o05,o06,o07,o08,o09,o10,o11,o12,o13,o14,o15;
    o00=o01=o02=o03=o04=o05=o06=o07=o08=o09=o10=o11=o12=o13=o14=o15=0.0f;
    float m_run = -1e30f, l_run = 0.0f;

    // L1 step: keys (bf16 frags) -> sigmoid(h1) into DST
    #define L1_STEP(AF0, AF1, DST)                                                   \
        _Pragma("unroll")                                                            \
        for (int nt = 0; nt < 5; ++nt) {                                             \
            float bb = base_c[nt];                                                   \
            f32x4 c = { bb, bb, bb, bb };                                            \
            c = __builtin_amdgcn_mfma_f32_16x16x32_bf16(AF0, bv[nt][0], c, 0, 0, 0); \
            c = __builtin_amdgcn_mfma_f32_16x16x32_bf16(AF1, bv[nt][1], c, 0, 0, 0); \
            _Pragma("unroll")                                                        \
            for (int r = 0; r < 4; ++r)                                              \
                (DST)[(g16 * 4 + r) * HSTR + nt * 16 + c16] = (__bf16)sigmoidf_(c[r]); \
        }

    // ---- pipeline prologue: L1(tile0) -> h1[0]; prefetch tile1 ----
    bf16x8 afc0, afc1, afn0, afn1;
    afc0[0]=(__bf16)u0.x; afc0[1]=(__bf16)u0.y; afc0[2]=(__bf16)u0.z; afc0[3]=(__bf16)u0.w;
    afc0[4]=(__bf16)u1.x; afc0[5]=(__bf16)u1.y; afc0[6]=(__bf16)u1.z; afc0[7]=(__bf16)u1.w;
    afc1[0]=(__bf16)u2.x; afc1[1]=(__bf16)u2.y; afc1[2]=(__bf16)u2.z; afc1[3]=(__bf16)u2.w;
    afc1[4]=(__bf16)u3.x; afc1[5]=(__bf16)u3.y; afc1[6]=(__bf16)u3.z; afc1[7]=(__bf16)u3.w;
    if (ntiles > 1) {
        int tr = 16 + c16;
        const float* kr = kb + (size_t)((tr < T_) ? tr : (T_ - 1)) * D_ + g16 * 8;
        u0 = *(const float4*)(kr);
        u1 = *(const float4*)(kr + 4);
        u2 = *(const float4*)(kr + 32);
        u3 = *(const float4*)(kr + 36);
    }
    L1_STEP(afc0, afc1, myh0)
    int cur = 0;

    // ---------------- main loop (software-pipelined) ----------------
    for (int tt = 0; tt < ntiles; ++tt) {
        __bf16* const hcur = myh0 + cur * HBUF;
        __bf16* const hnxt = myh0 + (cur ^ 1) * HBUF;

        // (1) read tile tt's h1 — writes completed last iteration; cheap wait
        bf16x8 a2_0 = *(const bf16x8*)&hcur[c16 * HSTR + g16 * 8];
        bf16x8 a2_1 = *(const bf16x8*)&hcur[c16 * HSTR + 32 + g16 * 8];
        bf16x8 a2_2 = *(const bf16x8*)&hcur[c16 * HSTR + 64 + g16 * 8];

        // (2) layer-2 MFMAs issue immediately
        f32x4 acc2[3];
        #pragma unroll
        for (int nt = 0; nt < 3; ++nt) {
            float bb = b2c[nt];
            f32x4 c = { bb, bb, bb, bb };
            c = __builtin_amdgcn_mfma_f32_16x16x32_bf16(a2_0, bw[nt][0], c, 0, 0, 0);
            c = __builtin_amdgcn_mfma_f32_16x16x32_bf16(a2_1, bw[nt][1], c, 0, 0, 0);
            c = __builtin_amdgcn_mfma_f32_16x16x32_bf16(a2_2, bw[nt][2], c, 0, 0, 0);
            acc2[nt] = c;
        }

        // (3) layer-1 of tile tt+1 into the other buffer (independent chain)
        const bool have_next = (tt + 1 < ntiles);
        if (have_next) {
            afn0[0]=(__bf16)u0.x; afn0[1]=(__bf16)u0.y; afn0[2]=(__bf16)u0.z; afn0[3]=(__bf16)u0.w;
            afn0[4]=(__bf16)u1.x; afn0[5]=(__bf16)u1.y; afn0[6]=(__bf16)u1.z; afn0[7]=(__bf16)u1.w;
            afn1[0]=(__bf16)u2.x; afn1[1]=(__bf16)u2.y; afn1[2]=(__bf16)u2.z; afn1[3]=(__bf16)u2.w;
            afn1[4]=(__bf16)u3.x; afn1[5]=(__bf16)u3.y; afn1[6]=(__bf16)u3.z; afn1[7]=(__bf16)u3.w;
            if (tt + 2 < ntiles) {
                int tr = (tt + 2) * 16 + c16;
                const float* kr = kb + (size_t)((tr < T_) ? tr : (T_ - 1)) * D_ + g16 * 8;
                u0 = *(const float4*)(kr);
                u1 = *(const float4*)(kr + 4);
                u2 = *(const float4*)(kr + 32);
                u3 = *(const float4*)(kr + 36);
            }
            L1_STEP(afn0, afn1, hnxt)
        }

        // (4) layer 3 + masked score of tile tt (VALU, interleaves with L1 chain)
        const int tb = tt * 16;
        #pragma unroll
        for (int r = 0; r < 4; ++r) {
            float partial = sigmoidf_(acc2[0][r]) * w3c[0]
                          + sigmoidf_(acc2[1][r]) * w3c[1]
                          + sigmoidf_(acc2[2][r]) * w3c[2];
            partial += __shfl_xor(partial, 1);
            partial += __shfl_xor(partial, 2);
            partial += __shfl_xor(partial, 4);
            partial += __shfl_xor(partial, 8);
            if (c16 == 0) {
                int t = tb + g16 * 4 + r;
                s_sc16[w][g16 * 4 + r] = (t < mv) ? (partial + b3v) * 0.125f : -1e30f;
            }
        }

        // online softmax + o-update (key values from afc = tile tt's bf16 frags)
        float s = s_sc16[w][c16];
        float tm = s;
        tm = fmaxf(tm, __shfl_xor(tm, 1));
        tm = fmaxf(tm, __shfl_xor(tm, 2));
        tm = fmaxf(tm, __shfl_xor(tm, 4));
        tm = fmaxf(tm, __shfl_xor(tm, 8));
        float m_new = fmaxf(m_run, tm);
        float alpha = __expf(m_run - m_new);
        float p = __expf(s - m_new);
        float psum = p;
        psum += __shfl_xor(psum, 1);
        psum += __shfl_xor(psum, 2);
        psum += __shfl_xor(psum, 4);
        psum += __shfl_xor(psum, 8);
        l_run = l_run * alpha + psum;
        o00 = fmaf(p, (float)afc0[0], o00 * alpha);  o01 = fmaf(p, (float)afc0[1], o01 * alpha);
        o02 = fmaf(p, (float)afc0[2], o02 * alpha);  o03 = fmaf(p, (float)afc0[3], o03 * alpha);
        o04 = fmaf(p, (float)afc0[4], o04 * alpha);  o05 = fmaf(p, (float)afc0[5], o05 * alpha);
        o06 = fmaf(p, (float)afc0[6], o06 * alpha);  o07 = fmaf(p, (float)afc0[7], o07 * alpha);
        o08 = fmaf(p, (float)afc1[0], o08 * alpha);  o09 = fmaf(p, (float)afc1[1], o09 * alpha);
        o10 = fmaf(p, (float)afc1[2], o10 * alpha);  o11 = fmaf(p, (float)afc1[3], o11 * alpha);
        o12 = fmaf(p, (float)afc1[4], o12 * alpha);  o13 = fmaf(p, (float)afc1[5], o13 * alpha);
        o14 = fmaf(p, (float)afc1[6], o14 * alpha);  o15 = fmaf(p, (float)afc1[7], o15 * alpha);
        m_run = m_new;

        if (have_next) { afc0 = afn0; afc1 = afn1; }
        cur ^= 1;
    }
    #undef L1_STEP

    // ---------------- finalize: reduce o over c16 lanes, normalize, store ----------------
    #define ORED(X) X += __shfl_xor(X,1); X += __shfl_xor(X,2); X += __shfl_xor(X,4); X += __shfl_xor(X,8);
    ORED(o00) ORED(o01) ORED(o02) ORED(o03) ORED(o04) ORED(o05) ORED(o06) ORED(o07)
    ORED(o08) ORED(o09) ORED(o10) ORED(o11) ORED(o12) ORED(o13) ORED(o14) ORED(o15)
    #undef ORED
    float inv_total = __builtin_amdgcn_rcpf(l_run);
    if (c16 == 0) {
        float* sp = &s_part[w][0];
        sp[g16 * 8 + 0] = o00;  sp[g16 * 8 + 1] = o01;
        sp[g16 * 8 + 2] = o02;  sp[g16 * 8 + 3] = o03;
        sp[g16 * 8 + 4] = o04;  sp[g16 * 8 + 5] = o05;
        sp[g16 * 8 + 6] = o06;  sp[g16 * 8 + 7] = o07;
        sp[32 + g16 * 8 + 0] = o08;  sp[32 + g16 * 8 + 1] = o09;
        sp[32 + g16 * 8 + 2] = o10;  sp[32 + g16 * 8 + 3] = o11;
        sp[32 + g16 * 8 + 4] = o12;  sp[32 + g16 * 8 + 5] = o13;
        sp[32 + g16 * 8 + 6] = o14;  sp[32 + g16 * 8 + 7] = o15;
    }
    asm volatile("s_waitcnt lgkmcnt(0)" ::: "memory");
    out[b * D_ + lane] = s_part[w][lane] * inv_total;
}

extern "C" void kernel_launch(void* const* d_in, const int* in_sizes, int n_in,
                              void* d_out, int out_size, void* d_ws, size_t ws_size,
                              hipStream_t stream)
{
    const float* query = (const float*)d_in[0];
    const float* key   = (const float*)d_in[1];
    const int*   mask  = (const int*)  d_in[2];
    const float* W1    = (const float*)d_in[3];
    const float* b1    = (const float*)d_in[4];
    const float* W2    = (const float*)d_in[5];
    const float* b2    = (const float*)d_in[6];
    const float* W3    = (const float*)d_in[7];
    const float* b3    = (const float*)d_in[8];
    float* out = (float*)d_out;

    prep_kernel<<<8, 256, 0, stream>>>(W1, W2, d_ws);
    attn_din15<<<512, 256, 0, stream>>>(query, key, mask, b1, b2, W3, b3, d_ws, out);
}